// Round 11
// baseline (138.096 us; speedup 1.0000x reference)
//
#include <hip/hip_runtime.h>

#define L_ATT 2304
// SCALE * log2(e): softmax via exp2 is mathematically identical
#define QSCALE_LOG2E 0.5100695712f

using bh8 = __attribute__((ext_vector_type(8))) short;  // 8 bf16 (4 VGPRs)
using f4  = __attribute__((ext_vector_type(4))) float;  // 4 fp32 acc

#if __has_builtin(__builtin_amdgcn_exp2f)
#define EXP2(x) __builtin_amdgcn_exp2f(x)
#else
#define EXP2(x) exp2f(x)
#endif

__device__ inline short f2b(float f) {   // RNE
    union { float f; unsigned u; } c; c.f = f;
    unsigned r = (c.u + 0x7FFFu + ((c.u >> 16) & 1u)) >> 16;
    return (short)r;
}
__device__ inline float b2f(short s) {
    union { unsigned u; float f; } c;
    c.u = ((unsigned)(unsigned short)s) << 16;
    return c.f;
}
// pack hi16(lo), hi16(hi) -> one dword (two bf16, truncation)
__device__ inline int packhi(float lo, float hi) {
    return (int)__builtin_amdgcn_perm(__float_as_uint(hi), __float_as_uint(lo), 0x07060302u);
}
// pack two RNE bf16 (k, k+1) into one dword — open-coded so the compiler can
// schedule it (R10 lesson: inline-asm v_cvt_pk_bf16_f32 serialized staging)
__device__ inline unsigned pk2(float lo, float hi) {
    return (unsigned)(unsigned short)f2b(lo) | ((unsigned)(unsigned short)f2b(hi) << 16);
}

// ---------------------------------------------------------------------------
// prep = weight conversion only (272 blocks x 256). xt transpose is fused
// into qkv's LDS staging — the 28MB xt round-trip is gone.
// ---------------------------------------------------------------------------
__global__ __launch_bounds__(256) void prep_kernel(
    const float* __restrict__ qkv_w, const float* __restrict__ res_w,
    const float* __restrict__ pos_w, short* __restrict__ wqb,
    short* __restrict__ reswb, short* __restrict__ wqp)
{
    int j = blockIdx.x * 256 + threadIdx.x;
    if (j < 24576) {
        float4 v = ((const float4*)qkv_w)[j];
        short4 o = { f2b(v.x), f2b(v.y), f2b(v.z), f2b(v.w) };
        *(short4*)(wqb + (size_t)j * 4) = o;
    } else if (j < 32768) {
        int idx = j - 24576;
        float4 v = ((const float4*)res_w)[idx];
        short4 o = { f2b(v.x), f2b(v.y), f2b(v.z), f2b(v.w) };
        *(short4*)(reswb + (size_t)idx * 4) = o;
    } else {
        int e = j - 32768;                 // e = q*4096 + (oc*64+ic)
        wqp[e] = f2b(pos_w[(size_t)(e & 4095) * 9 + (e >> 12)]);
    }
}

// ---------------------------------------------------------------------------
// qkv 1x1 conv as MFMA GEMM, 32-wide l-tiles. Stages the B panel DIRECTLY
// from fp32 x with an in-LDS transpose — each thread loads 8 row-pairs
// (16 float4, 128B-coalesced per 8 lanes), packs k/k+1 bf16 pairs (RNE f2b,
// open-coded pk2) into [32][522] LDS (row stride 261 dwords == 5 mod 32 ->
// write group spreads 2 lanes/bank, free). The 3 y-sibling blocks per
// (l0,n) share an XCD (same g&7) -> x re-reads are L2 hits. Inner loop:
// 1 global A + 2 ds_read_b128 + 2 MFMA. Flat grid 864 = 8*108, XCD-swizzled.
// Epilogue: q->qt8, k->kt8, v->vt+vle.
// ---------------------------------------------------------------------------
__global__ __launch_bounds__(256) void qkv_kernel(
    const float* __restrict__ x, const short* __restrict__ wqb,
    const float* __restrict__ qkv_b, short* __restrict__ qt8,
    short* __restrict__ kt8, short* __restrict__ vt, short* __restrict__ vle)
{
    __shared__ short bs[32 * 522];         // 33408 B, [l][k] padded +10 shorts
    const int g = blockIdx.x;              // 864 = 8 * 108
    const int xcd = g & 7, rr = g >> 3;    // rr < 108
    const int y = rr % 3, grp = rr / 3;    // grp < 36
    const int code = grp * 8 + xcd;        // = ltile + 72*n, < 288
    const int l0 = (code % 72) * 32, oc0 = y * 64, n = code / 72;

    const int tid = threadIdx.x;
    const int lane = tid & 63, wave = tid >> 6;
    const int col = lane & 15, quad = lane >> 4;
    const int ocb = oc0 + wave * 16;

    // stage B panel from x with fused transpose+cvt: 256 k-pairs x 8 l-quads
    {
        const float* src = x + (size_t)n * 512 * L_ATT + l0;
#pragma unroll
        for (int j = 0; j < 8; ++j) {
            int idx = j * 256 + tid;       // 0..2047
            int k2 = (idx >> 3) * 2;       // even k row
            int lq = (idx & 7) * 4;        // l quad base
            float4 av = *(const float4*)(src + (size_t)k2 * L_ATT + lq);
            float4 bv = *(const float4*)(src + (size_t)(k2 + 1) * L_ATT + lq);
            *(unsigned*)&bs[(lq + 0) * 522 + k2] = pk2(av.x, bv.x);
            *(unsigned*)&bs[(lq + 1) * 522 + k2] = pk2(av.y, bv.y);
            *(unsigned*)&bs[(lq + 2) * 522 + k2] = pk2(av.z, bv.z);
            *(unsigned*)&bs[(lq + 3) * 522 + k2] = pk2(av.w, bv.w);
        }
    }
    __syncthreads();

    f4 acc[2];
    acc[0] = (f4){0.f, 0.f, 0.f, 0.f};
    acc[1] = (f4){0.f, 0.f, 0.f, 0.f};

    const short* arow = wqb + (size_t)(ocb + col) * 512 + quad * 8;
    const short* b0p = bs + col * 522 + quad * 8;
    const short* b1p = b0p + 16 * 522;

#pragma unroll 4
    for (int k0 = 0; k0 < 512; k0 += 32) {
        bh8 af = *(const bh8*)(arow + k0);
        bh8 b0 = *(const bh8*)(b0p + k0);
        bh8 b1 = *(const bh8*)(b1p + k0);
        acc[0] = __builtin_amdgcn_mfma_f32_16x16x32_bf16(af, b0, acc[0], 0, 0, 0);
        acc[1] = __builtin_amdgcn_mfma_f32_16x16x32_bf16(af, b1, acc[1], 0, 0, 0);
    }

    const int obase = ocb + quad * 4;       // multiple of 4; r0 never straddles
    const int h = obase / 24;
    const int r0 = obase - h * 24;
    const int slice = n * 8 + h;

#pragma unroll
    for (int nt = 0; nt < 2; ++nt) {
        int l = l0 + nt * 16 + col;
        float v[4];
#pragma unroll
        for (int reg = 0; reg < 4; ++reg) v[reg] = acc[nt][reg] + qkv_b[obase + reg];
        if (r0 < 8) {          // q: scale, pack short4
            short4 o = { f2b(v[0] * QSCALE_LOG2E), f2b(v[1] * QSCALE_LOG2E),
                         f2b(v[2] * QSCALE_LOG2E), f2b(v[3] * QSCALE_LOG2E) };
            *(short4*)(qt8 + ((size_t)slice * L_ATT + l) * 8 + r0) = o;
        } else if (r0 < 16) {  // k
            short4 o = { f2b(v[0]), f2b(v[1]), f2b(v[2]), f2b(v[3]) };
            *(short4*)(kt8 + ((size_t)slice * L_ATT + l) * 8 + (r0 - 8)) = o;
        } else {               // v
            short4 o = { f2b(v[0]), f2b(v[1]), f2b(v[2]), f2b(v[3]) };
            int d0 = r0 - 16;
#pragma unroll
            for (int reg = 0; reg < 4; ++reg)
                vt[((size_t)slice * 8 + d0 + reg) * L_ATT + l] = ((short*)&o)[reg];
            *(short4*)(vle + ((size_t)n * L_ATT + l) * 64 + h * 8 + d0) = o;
        }
    }
}

// ---------------------------------------------------------------------------
// attnpos: split-K(2) flash attention (g<1152) U 3x3 pos-conv (g>=1152).
// attn block = 128 queries x 1152 keys. 3 K/V sub-tiles per barrier
// (6 syncs); staging spread over all 4 waves (waves 0-2: K subs,
// wave 3 + waves 0/1 second-load: V subs). Double-buffered 6-slot LDS
// (12.3KB). setprio(1) around each compute cluster. Flat tile order
// (t,u,ks) -> bit-identical output. 1728 blocks, h = g&7. (R8 version —
// R9's single-shot staging traded occupancy 8->4 blocks/CU and regressed.)
// ---------------------------------------------------------------------------
__global__ __launch_bounds__(256) void attnpos_kernel(
    const short* __restrict__ qt8, const short* __restrict__ kt8,
    const short* __restrict__ vt, const short* __restrict__ vle,
    const short* __restrict__ wqp, const float* __restrict__ pbias,
    float* __restrict__ pnum, float* __restrict__ pls, short* __restrict__ pcv)
{
    __shared__ short smem[6160];   // K: 2buf x 3sub x 512 @0, V same @3072, ones @6144
    const int g = blockIdx.x;
    const int tid = threadIdx.x;
    const int lane = tid & 63, wave = tid >> 6;
    const int col = lane & 15, quad = lane >> 4;

    if (g < 1152) {                        // ---- attention half (split-K 2) ----
        const int h = g & 7, r = g >> 3;   // r < 144 = n(4) x qt(18) x half(2)
        const int n = r / 36;
        const int rem = r - n * 36;
        const int qt = rem >> 1, half = rem & 1;
        const int q0 = qt * 128;
        const int kbase = half * 1152;
        const int slice = n * 8 + h;

        const short* qs  = qt8 + (size_t)slice * L_ATT * 8;
        const short* ks8 = kt8 + (size_t)slice * L_ATT * 8;
        const short* vb  = vt  + (size_t)slice * 8 * L_ATT;

        if (tid < 16) smem[6144 + tid] = (tid < 8) ? (short)0x3F80 : (short)0;

        bh8 zero8 = {0, 0, 0, 0, 0, 0, 0, 0};
        bh8 qf[2];
#pragma unroll
        for (int f = 0; f < 2; ++f) {
            qf[f] = zero8;
            if (quad == 0)
                qf[f] = *(const bh8*)(qs + (size_t)(q0 + wave * 32 + f * 16 + col) * 8);
        }

        // per-slot read offsets (buf/sub = p*1536 + u*512 added at use, gated)
        int kidx[4];
#pragma unroll
        for (int nt = 0; nt < 4; ++nt)
            kidx[nt] = (quad == 0) ? (nt * 16 + col) * 8 : 6152;
        int vidx[2];
#pragma unroll
        for (int ks = 0; ks < 2; ++ks)
            vidx[ks] = (col < 8)
                     ? col * 64 + ((ks * 32 + quad * 8 + col * 8) & 63)
                     : ((col == 8) ? 6144 : 6152);

        const int ksl = ((lane >> 5) & 1) * 32 + ((lane >> 2) & 1) * 16
                      + ((lane >> 3) & 3) * 4 + (lane & 3);
        const int vd = lane >> 3, vkc = (lane & 7) * 8;
        const int vsl = vd * 64 + ((vkc + vd * 8) & 63);

        // prologue: stage sub-tiles 0,1,2 into buffer 0
        if (wave < 3)
            *(uint4*)&smem[wave * 512 + ksl * 8] =
                *(const uint4*)(ks8 + (size_t)(kbase + wave * 64 + lane) * 8);
        else
            *(uint4*)&smem[3072 + vsl] =
                *(const uint4*)(vb + (size_t)vd * L_ATT + kbase + vkc);
        if (wave == 0)
            *(uint4*)&smem[3072 + 512 + vsl] =
                *(const uint4*)(vb + (size_t)vd * L_ATT + kbase + 64 + vkc);
        else if (wave == 1)
            *(uint4*)&smem[3072 + 1024 + vsl] =
                *(const uint4*)(vb + (size_t)vd * L_ATT + kbase + 128 + vkc);
        __syncthreads();

        f4 oacc[2];
        oacc[0] = (f4){0.f, 0.f, 0.f, 0.f};
        oacc[1] = (f4){0.f, 0.f, 0.f, 0.f};

        int p = 0;
        for (int t = 0; t < 6; ++t) {
            // issue next step's global loads NOW (t=5 overrun stays inside ws)
            uint4 dA, dB;
            if (wave < 3)
                dA = *(const uint4*)(ks8 + (size_t)(kbase + (t * 3 + 3 + wave) * 64 + lane) * 8);
            else
                dA = *(const uint4*)(vb + (size_t)vd * L_ATT + kbase + (t * 3 + 3) * 64 + vkc);
            if (wave == 0)
                dB = *(const uint4*)(vb + (size_t)vd * L_ATT + kbase + (t * 3 + 4) * 64 + vkc);
            else if (wave == 1)
                dB = *(const uint4*)(vb + (size_t)vd * L_ATT + kbase + (t * 3 + 5) * 64 + vkc);

#pragma unroll
            for (int u = 0; u < 3; ++u) {
                const int ku = (quad == 0) ? p * 1536 + u * 512 : 0;
                const int vu = (col < 8) ? 3072 + p * 1536 + u * 512 : 0;
                bh8 kf[4], vf[2];
#pragma unroll
                for (int nt = 0; nt < 4; ++nt) kf[nt] = *(const bh8*)&smem[kidx[nt] + ku];
#pragma unroll
                for (int ks = 0; ks < 2; ++ks) vf[ks] = *(const bh8*)&smem[vidx[ks] + vu];

                __builtin_amdgcn_s_setprio(1);
#pragma unroll
                for (int f = 0; f < 2; ++f) {
                    f4 s[4];
#pragma unroll
                    for (int nt = 0; nt < 4; ++nt) {
                        f4 z = (f4){0.f, 0.f, 0.f, 0.f};
                        s[nt] = __builtin_amdgcn_mfma_f32_16x16x32_bf16(kf[nt], qf[f], z, 0, 0, 0);
                    }
                    float e[4][4];
#pragma unroll
                    for (int nt = 0; nt < 4; ++nt)
#pragma unroll
                        for (int reg = 0; reg < 4; ++reg)
                            e[nt][reg] = EXP2(s[nt][reg]);
#pragma unroll
                    for (int ks = 0; ks < 2; ++ks) {
                        union { int i[4]; bh8 v; } pu;
                        pu.i[0] = packhi(e[2 * ks][0],     e[2 * ks][1]);
                        pu.i[1] = packhi(e[2 * ks][2],     e[2 * ks][3]);
                        pu.i[2] = packhi(e[2 * ks + 1][0], e[2 * ks + 1][1]);
                        pu.i[3] = packhi(e[2 * ks + 1][2], e[2 * ks + 1][3]);
                        oacc[f] = __builtin_amdgcn_mfma_f32_16x16x32_bf16(vf[ks], pu.v, oacc[f], 0, 0, 0);
                    }
                }
                __builtin_amdgcn_s_setprio(0);
            }

            if (wave < 3)
                *(uint4*)&smem[(p ^ 1) * 1536 + wave * 512 + ksl * 8] = dA;
            else
                *(uint4*)&smem[3072 + (p ^ 1) * 1536 + vsl] = dA;
            if (wave == 0)
                *(uint4*)&smem[3072 + (p ^ 1) * 1536 + 512 + vsl] = dB;
            else if (wave == 1)
                *(uint4*)&smem[3072 + (p ^ 1) * 1536 + 1024 + vsl] = dB;
            p ^= 1;
            __syncthreads();
        }

        // partials: quad0 -> d0..3, quad1 -> d4..7, quad2/reg0 -> lsum
        const size_t prow = (size_t)(slice * 2 + half) * L_ATT;
#pragma unroll
        for (int f = 0; f < 2; ++f) {
            int qg = q0 + wave * 32 + f * 16 + col;
            if (quad < 2) {
                float4 o = { oacc[f][0], oacc[f][1], oacc[f][2], oacc[f][3] };
                *(float4*)(pnum + (prow + qg) * 8 + quad * 4) = o;
            } else if (quad == 2) {
                pls[prow + qg] = oacc[f][0];
            }
        }
        return;
    }

    // ---- posconv half ----
    const int gf = g - 1152;               // 576 = 144 * 4
    const int l0 = (gf % 144) * 16, n = gf / 144;
    const int t = wave;                    // oc-strip = wave id

    const int la = l0 + col;
    const int ya = la / 48, xa = la - ya * 48;

    f4 acc = (f4){0.f, 0.f, 0.f, 0.f};
    const short* vbase = vle + (size_t)n * L_ATT * 64;

#pragma unroll
    for (int q = 0; q < 9; ++q) {
        const int dy = q / 3 - 1, dx = q - (q / 3) * 3 - 1;
        const bool valid = ((unsigned)(ya + dy) < 48u) && ((unsigned)(xa + dx) < 48u);
        const short* ap = vbase + (size_t)(la + dy * 48 + dx) * 64 + quad * 8;
#pragma unroll
        for (int ks = 0; ks < 2; ++ks) {
            bh8 af = {0, 0, 0, 0, 0, 0, 0, 0};
            if (valid) af = *(const bh8*)(ap + ks * 32);
            bh8 bf = *(const bh8*)(wqp + ((size_t)q * 64 + t * 16 + col) * 64
                                   + ks * 32 + quad * 8);
            acc = __builtin_amdgcn_mfma_f32_16x16x32_bf16(af, bf, acc, 0, 0, 0);
        }
    }

    short* op = pcv + (size_t)n * L_ATT * 64;
    const int oc = t * 16 + col;
    const float bb = pbias[oc];
#pragma unroll
    for (int reg = 0; reg < 4; ++reg) {
        int l = l0 + quad * 4 + reg;
        op[(size_t)l * 64 + oc] = f2b(acc[reg] + bb);
    }
}

// ---------------------------------------------------------------------------
// comb: split-K combine + pcv add, packed bf16 ONCE per (n,l,ch) instead of
// once per oc-tile inside res (8x redundancy). battp[n][l][64] is bit-
// identical to the B-fragments res built in R4 (same packhi truncation).
// 576 blocks x 256: thread = (n, l, half-head); 16 lanes write 128B rows.
// ---------------------------------------------------------------------------
__global__ __launch_bounds__(256) void comb_kernel(
    const float* __restrict__ pnum, const float* __restrict__ pls,
    const short* __restrict__ pcv, short* __restrict__ battp)
{
    const int b = blockIdx.x;              // 576 = 4n * 144 lt
    const int n = b / 144, lt = b % 144;
    const int hh = threadIdx.x & 15;       // half-head: h = hh>>1, d-half = hh&1
    const int l  = lt * 16 + (threadIdx.x >> 4);
    const int h = hh >> 1, dh = hh & 1;

    const size_t p0 = (size_t)((n * 8 + h) * 2) * L_ATT;
    const size_t p1 = p0 + L_ATT;
    float4 a = *(const float4*)(pnum + (p0 + l) * 8 + dh * 4);
    float4 c = *(const float4*)(pnum + (p1 + l) * 8 + dh * 4);
    float inv = 1.0f / (pls[p0 + l] + pls[p1 + l]);
    short4 pv = *(const short4*)(pcv + ((size_t)n * L_ATT + l) * 64 + hh * 4);

    int2 o;
    o.x = packhi((a.x + c.x) * inv + b2f(pv.x), (a.y + c.y) * inv + b2f(pv.y));
    o.y = packhi((a.z + c.z) * inv + b2f(pv.z), (a.w + c.w) * inv + b2f(pv.w));
    *(int2*)(battp + ((size_t)n * L_ATT + l) * 64 + hh * 4) = o;
}

// ---------------------------------------------------------------------------
// res 1x1 conv, K=64: out = W.battp + res_b — pure GEMM, B-fragment is a
// single bh8 load (combine hoisted into comb_kernel). Flat grid 1152,
// XCD-swizzled; all 4 waves share the block's 8KB B panel via L1.
// ---------------------------------------------------------------------------
__global__ __launch_bounds__(256) void res_kernel(
    const short* __restrict__ battp, const short* __restrict__ reswb,
    const float* __restrict__ res_b, float* __restrict__ out)
{
    const int g = blockIdx.x;              // 1152 = 8 * 144
    const int xcd = g & 7, rr = g >> 3;    // rr < 144
    const int y = rr & 7, grp = rr >> 3;   // grp < 18
    const int code = grp * 8 + xcd;        // < 144
    const int l0 = (code % 36) * 64, oc0 = y * 64, n = code / 36;

    const int lane = threadIdx.x & 63, wave = threadIdx.x >> 6;
    const int col = lane & 15, quad = lane >> 4;
    const int ocb = oc0 + wave * 16;

    f4 acc[4];
#pragma unroll
    for (int nt = 0; nt < 4; ++nt) acc[nt] = (f4){0.f, 0.f, 0.f, 0.f};

#pragma unroll
    for (int ks = 0; ks < 2; ++ks) {
        bh8 af = *(const bh8*)(reswb + (size_t)(ocb + col) * 64 + ks * 32 + quad * 8);
        const int ch = ks * 32 + quad * 8;
#pragma unroll
        for (int nt = 0; nt < 4; ++nt) {
            const int l = l0 + nt * 16 + col;
            bh8 bf = *(const bh8*)(battp + ((size_t)n * L_ATT + l) * 64 + ch);
            acc[nt] = __builtin_amdgcn_mfma_f32_16x16x32_bf16(af, bf, acc[nt], 0, 0, 0);
        }
    }

#pragma unroll
    for (int nt = 0; nt < 4; ++nt) {
        int l = l0 + nt * 16 + col;
#pragma unroll
        for (int reg = 0; reg < 4; ++reg) {
            int oc = ocb + quad * 4 + reg;
            out[((size_t)n * 512 + oc) * L_ATT + l] = acc[nt][reg] + res_b[oc];
        }
    }
}

// ---------------------------------------------------------------------------
extern "C" void kernel_launch(void* const* d_in, const int* in_sizes, int n_in,
                              void* d_out, int out_size, void* d_ws, size_t ws_size,
                              hipStream_t stream)
{
    const float* x      = (const float*)d_in[0];
    const float* qkv_w  = (const float*)d_in[1];
    const float* qkv_b  = (const float*)d_in[2];
    const float* pos_w  = (const float*)d_in[3];
    const float* pos_b  = (const float*)d_in[4];
    const float* res_w  = (const float*)d_in[5];
    const float* res_b  = (const float*)d_in[6];
    float* out = (float*)d_out;

    char* ws = (char*)d_ws;
    float* pnum  = (float*)(ws);                    //  4,718,592 B: [64][2304][8]
    float* pls   = (float*)(ws + 4718592);          //    589,824 B: [64][2304]
    short* qt8   = (short*)(ws + 9437184);          //  1,179,648 B: [32][2304][8]
    short* kt8   = (short*)(ws + 10616832);         //  1,179,648 B: [32][2304][8]
    short* vt    = (short*)(ws + 11796480);         //  1,179,648 B: [32][8][2304]
    short* pcv   = (short*)(ws + 12976128);         //  1,179,648 B: [4][2304][64]
    short* wqb   = (short*)(ws + 14155776);         //    196,608 B: [192][512]
    short* reswb = (short*)(ws + 14352384);         //     65,536 B: [512][64]
    short* vle   = (short*)(ws + 14417920);         //  1,179,648 B: [4][2304][64]
    short* wqp   = (short*)(ws + 15597568);         //     73,728 B: [9][64][64]
    short* battp = (short*)(ws + 15671296);         //  1,179,648 B: [4][2304][64]

    prep_kernel<<<272, 256, 0, stream>>>(qkv_w, res_w, pos_w, wqb, reswb, wqp);
    qkv_kernel<<<864, 256, 0, stream>>>(x, wqb, qkv_b, qt8, kt8, vt, vle);
    attnpos_kernel<<<1728, 256, 0, stream>>>(qt8, kt8, vt, vle, wqp, pos_b, pnum, pls, pcv);
    comb_kernel<<<576, 256, 0, stream>>>(pnum, pls, pcv, battp);
    res_kernel<<<1152, 256, 0, stream>>>(battp, reswb, res_b, out);
}

// Round 12
// 132.244 us; speedup vs baseline: 1.0442x; 1.0442x over previous
//
#include <hip/hip_runtime.h>

#define L_ATT 2304
// SCALE * log2(e): softmax via exp2 is mathematically identical
#define QSCALE_LOG2E 0.5100695712f

using bh8 = __attribute__((ext_vector_type(8))) short;  // 8 bf16 (4 VGPRs)
using f4  = __attribute__((ext_vector_type(4))) float;  // 4 fp32 acc

#if __has_builtin(__builtin_amdgcn_exp2f)
#define EXP2(x) __builtin_amdgcn_exp2f(x)
#else
#define EXP2(x) exp2f(x)
#endif

__device__ inline short f2b(float f) {   // RNE
    union { float f; unsigned u; } c; c.f = f;
    unsigned r = (c.u + 0x7FFFu + ((c.u >> 16) & 1u)) >> 16;
    return (short)r;
}
__device__ inline float b2f(short s) {
    union { unsigned u; float f; } c;
    c.u = ((unsigned)(unsigned short)s) << 16;
    return c.f;
}
// pack hi16(lo), hi16(hi) -> one dword (two bf16, truncation)
__device__ inline int packhi(float lo, float hi) {
    return (int)__builtin_amdgcn_perm(__float_as_uint(hi), __float_as_uint(lo), 0x07060302u);
}
// pack two RNE bf16 (k, k+1) into one dword — open-coded so the compiler can
// schedule it (R10 lesson: inline-asm v_cvt_pk_bf16_f32 serialized staging).
// R11 lesson: LDS row stride must keep 16B alignment for ds_read_b128 —
// pad must be a multiple of 8 shorts; 520 is the choice (write-side 4-way
// alias on stores is cheap and hidden).
__device__ inline unsigned pk2(float lo, float hi) {
    return (unsigned)(unsigned short)f2b(lo) | ((unsigned)(unsigned short)f2b(hi) << 16);
}

// ---------------------------------------------------------------------------
// prep = weight conversion only (272 blocks x 256). xt transpose is fused
// into qkv's LDS staging — the 28MB xt round-trip is gone.
// ---------------------------------------------------------------------------
__global__ __launch_bounds__(256) void prep_kernel(
    const float* __restrict__ qkv_w, const float* __restrict__ res_w,
    const float* __restrict__ pos_w, short* __restrict__ wqb,
    short* __restrict__ reswb, short* __restrict__ wqp)
{
    int j = blockIdx.x * 256 + threadIdx.x;
    if (j < 24576) {
        float4 v = ((const float4*)qkv_w)[j];
        short4 o = { f2b(v.x), f2b(v.y), f2b(v.z), f2b(v.w) };
        *(short4*)(wqb + (size_t)j * 4) = o;
    } else if (j < 32768) {
        int idx = j - 24576;
        float4 v = ((const float4*)res_w)[idx];
        short4 o = { f2b(v.x), f2b(v.y), f2b(v.z), f2b(v.w) };
        *(short4*)(reswb + (size_t)idx * 4) = o;
    } else {
        int e = j - 32768;                 // e = q*4096 + (oc*64+ic)
        wqp[e] = f2b(pos_w[(size_t)(e & 4095) * 9 + (e >> 12)]);
    }
}

// ---------------------------------------------------------------------------
// qkv 1x1 conv as MFMA GEMM, 32-wide l-tiles. Stages the B panel DIRECTLY
// from fp32 x with an in-LDS transpose — each thread loads 8 row-pairs
// (16 float4, 128B-coalesced per 8 lanes), packs k/k+1 bf16 pairs (RNE f2b)
// into [32][520] LDS (row stride 1040 B = 65x16: ds_read_b128 alignment
// preserved — R11 lesson). The 3 y-sibling blocks per (l0,n) share an XCD
// (same g&7) -> x re-reads are L2 hits. Inner loop: 1 global A + 2
// ds_read_b128 + 2 MFMA. Flat grid 864 = 8*108, XCD-swizzled.
// Epilogue: q->qt8, k->kt8, v->vt+vle.
// ---------------------------------------------------------------------------
__global__ __launch_bounds__(256) void qkv_kernel(
    const float* __restrict__ x, const short* __restrict__ wqb,
    const float* __restrict__ qkv_b, short* __restrict__ qt8,
    short* __restrict__ kt8, short* __restrict__ vt, short* __restrict__ vle)
{
    __shared__ short bs[32 * 520];         // 33280 B, [l][k] padded +8 shorts
    const int g = blockIdx.x;              // 864 = 8 * 108
    const int xcd = g & 7, rr = g >> 3;    // rr < 108
    const int y = rr % 3, grp = rr / 3;    // grp < 36
    const int code = grp * 8 + xcd;        // = ltile + 72*n, < 288
    const int l0 = (code % 72) * 32, oc0 = y * 64, n = code / 72;

    const int tid = threadIdx.x;
    const int lane = tid & 63, wave = tid >> 6;
    const int col = lane & 15, quad = lane >> 4;
    const int ocb = oc0 + wave * 16;

    // stage B panel from x with fused transpose+cvt: 256 k-pairs x 8 l-quads
    {
        const float* src = x + (size_t)n * 512 * L_ATT + l0;
#pragma unroll
        for (int j = 0; j < 8; ++j) {
            int idx = j * 256 + tid;       // 0..2047
            int k2 = (idx >> 3) * 2;       // even k row
            int lq = (idx & 7) * 4;        // l quad base
            float4 av = *(const float4*)(src + (size_t)k2 * L_ATT + lq);
            float4 bv = *(const float4*)(src + (size_t)(k2 + 1) * L_ATT + lq);
            *(unsigned*)&bs[(lq + 0) * 520 + k2] = pk2(av.x, bv.x);
            *(unsigned*)&bs[(lq + 1) * 520 + k2] = pk2(av.y, bv.y);
            *(unsigned*)&bs[(lq + 2) * 520 + k2] = pk2(av.z, bv.z);
            *(unsigned*)&bs[(lq + 3) * 520 + k2] = pk2(av.w, bv.w);
        }
    }
    __syncthreads();

    f4 acc[2];
    acc[0] = (f4){0.f, 0.f, 0.f, 0.f};
    acc[1] = (f4){0.f, 0.f, 0.f, 0.f};

    const short* arow = wqb + (size_t)(ocb + col) * 512 + quad * 8;
    const short* b0p = bs + col * 520 + quad * 8;
    const short* b1p = b0p + 16 * 520;

#pragma unroll 4
    for (int k0 = 0; k0 < 512; k0 += 32) {
        bh8 af = *(const bh8*)(arow + k0);
        bh8 b0 = *(const bh8*)(b0p + k0);
        bh8 b1 = *(const bh8*)(b1p + k0);
        acc[0] = __builtin_amdgcn_mfma_f32_16x16x32_bf16(af, b0, acc[0], 0, 0, 0);
        acc[1] = __builtin_amdgcn_mfma_f32_16x16x32_bf16(af, b1, acc[1], 0, 0, 0);
    }

    const int obase = ocb + quad * 4;       // multiple of 4; r0 never straddles
    const int h = obase / 24;
    const int r0 = obase - h * 24;
    const int slice = n * 8 + h;

#pragma unroll
    for (int nt = 0; nt < 2; ++nt) {
        int l = l0 + nt * 16 + col;
        float v[4];
#pragma unroll
        for (int reg = 0; reg < 4; ++reg) v[reg] = acc[nt][reg] + qkv_b[obase + reg];
        if (r0 < 8) {          // q: scale, pack short4
            short4 o = { f2b(v[0] * QSCALE_LOG2E), f2b(v[1] * QSCALE_LOG2E),
                         f2b(v[2] * QSCALE_LOG2E), f2b(v[3] * QSCALE_LOG2E) };
            *(short4*)(qt8 + ((size_t)slice * L_ATT + l) * 8 + r0) = o;
        } else if (r0 < 16) {  // k
            short4 o = { f2b(v[0]), f2b(v[1]), f2b(v[2]), f2b(v[3]) };
            *(short4*)(kt8 + ((size_t)slice * L_ATT + l) * 8 + (r0 - 8)) = o;
        } else {               // v
            short4 o = { f2b(v[0]), f2b(v[1]), f2b(v[2]), f2b(v[3]) };
            int d0 = r0 - 16;
#pragma unroll
            for (int reg = 0; reg < 4; ++reg)
                vt[((size_t)slice * 8 + d0 + reg) * L_ATT + l] = ((short*)&o)[reg];
            *(short4*)(vle + ((size_t)n * L_ATT + l) * 64 + h * 8 + d0) = o;
        }
    }
}

// ---------------------------------------------------------------------------
// attnpos: split-K(2) flash attention (g<1152) U 3x3 pos-conv (g>=1152).
// attn block = 128 queries x 1152 keys. 3 K/V sub-tiles per barrier
// (6 syncs); staging spread over all 4 waves (waves 0-2: K subs,
// wave 3 + waves 0/1 second-load: V subs). Double-buffered 6-slot LDS
// (12.3KB). setprio(1) around each compute cluster. Flat tile order
// (t,u,ks) -> bit-identical output. 1728 blocks, h = g&7. (R8 version —
// R9's single-shot staging traded occupancy 8->4 blocks/CU and regressed.)
// ---------------------------------------------------------------------------
__global__ __launch_bounds__(256) void attnpos_kernel(
    const short* __restrict__ qt8, const short* __restrict__ kt8,
    const short* __restrict__ vt, const short* __restrict__ vle,
    const short* __restrict__ wqp, const float* __restrict__ pbias,
    float* __restrict__ pnum, float* __restrict__ pls, short* __restrict__ pcv)
{
    __shared__ short smem[6160];   // K: 2buf x 3sub x 512 @0, V same @3072, ones @6144
    const int g = blockIdx.x;
    const int tid = threadIdx.x;
    const int lane = tid & 63, wave = tid >> 6;
    const int col = lane & 15, quad = lane >> 4;

    if (g < 1152) {                        // ---- attention half (split-K 2) ----
        const int h = g & 7, r = g >> 3;   // r < 144 = n(4) x qt(18) x half(2)
        const int n = r / 36;
        const int rem = r - n * 36;
        const int qt = rem >> 1, half = rem & 1;
        const int q0 = qt * 128;
        const int kbase = half * 1152;
        const int slice = n * 8 + h;

        const short* qs  = qt8 + (size_t)slice * L_ATT * 8;
        const short* ks8 = kt8 + (size_t)slice * L_ATT * 8;
        const short* vb  = vt  + (size_t)slice * 8 * L_ATT;

        if (tid < 16) smem[6144 + tid] = (tid < 8) ? (short)0x3F80 : (short)0;

        bh8 zero8 = {0, 0, 0, 0, 0, 0, 0, 0};
        bh8 qf[2];
#pragma unroll
        for (int f = 0; f < 2; ++f) {
            qf[f] = zero8;
            if (quad == 0)
                qf[f] = *(const bh8*)(qs + (size_t)(q0 + wave * 32 + f * 16 + col) * 8);
        }

        // per-slot read offsets (buf/sub = p*1536 + u*512 added at use, gated)
        int kidx[4];
#pragma unroll
        for (int nt = 0; nt < 4; ++nt)
            kidx[nt] = (quad == 0) ? (nt * 16 + col) * 8 : 6152;
        int vidx[2];
#pragma unroll
        for (int ks = 0; ks < 2; ++ks)
            vidx[ks] = (col < 8)
                     ? col * 64 + ((ks * 32 + quad * 8 + col * 8) & 63)
                     : ((col == 8) ? 6144 : 6152);

        const int ksl = ((lane >> 5) & 1) * 32 + ((lane >> 2) & 1) * 16
                      + ((lane >> 3) & 3) * 4 + (lane & 3);
        const int vd = lane >> 3, vkc = (lane & 7) * 8;
        const int vsl = vd * 64 + ((vkc + vd * 8) & 63);

        // prologue: stage sub-tiles 0,1,2 into buffer 0
        if (wave < 3)
            *(uint4*)&smem[wave * 512 + ksl * 8] =
                *(const uint4*)(ks8 + (size_t)(kbase + wave * 64 + lane) * 8);
        else
            *(uint4*)&smem[3072 + vsl] =
                *(const uint4*)(vb + (size_t)vd * L_ATT + kbase + vkc);
        if (wave == 0)
            *(uint4*)&smem[3072 + 512 + vsl] =
                *(const uint4*)(vb + (size_t)vd * L_ATT + kbase + 64 + vkc);
        else if (wave == 1)
            *(uint4*)&smem[3072 + 1024 + vsl] =
                *(const uint4*)(vb + (size_t)vd * L_ATT + kbase + 128 + vkc);
        __syncthreads();

        f4 oacc[2];
        oacc[0] = (f4){0.f, 0.f, 0.f, 0.f};
        oacc[1] = (f4){0.f, 0.f, 0.f, 0.f};

        int p = 0;
        for (int t = 0; t < 6; ++t) {
            // issue next step's global loads NOW (t=5 overrun stays inside ws)
            uint4 dA, dB;
            if (wave < 3)
                dA = *(const uint4*)(ks8 + (size_t)(kbase + (t * 3 + 3 + wave) * 64 + lane) * 8);
            else
                dA = *(const uint4*)(vb + (size_t)vd * L_ATT + kbase + (t * 3 + 3) * 64 + vkc);
            if (wave == 0)
                dB = *(const uint4*)(vb + (size_t)vd * L_ATT + kbase + (t * 3 + 4) * 64 + vkc);
            else if (wave == 1)
                dB = *(const uint4*)(vb + (size_t)vd * L_ATT + kbase + (t * 3 + 5) * 64 + vkc);

#pragma unroll
            for (int u = 0; u < 3; ++u) {
                const int ku = (quad == 0) ? p * 1536 + u * 512 : 0;
                const int vu = (col < 8) ? 3072 + p * 1536 + u * 512 : 0;
                bh8 kf[4], vf[2];
#pragma unroll
                for (int nt = 0; nt < 4; ++nt) kf[nt] = *(const bh8*)&smem[kidx[nt] + ku];
#pragma unroll
                for (int ks = 0; ks < 2; ++ks) vf[ks] = *(const bh8*)&smem[vidx[ks] + vu];

                __builtin_amdgcn_s_setprio(1);
#pragma unroll
                for (int f = 0; f < 2; ++f) {
                    f4 s[4];
#pragma unroll
                    for (int nt = 0; nt < 4; ++nt) {
                        f4 z = (f4){0.f, 0.f, 0.f, 0.f};
                        s[nt] = __builtin_amdgcn_mfma_f32_16x16x32_bf16(kf[nt], qf[f], z, 0, 0, 0);
                    }
                    float e[4][4];
#pragma unroll
                    for (int nt = 0; nt < 4; ++nt)
#pragma unroll
                        for (int reg = 0; reg < 4; ++reg)
                            e[nt][reg] = EXP2(s[nt][reg]);
#pragma unroll
                    for (int ks = 0; ks < 2; ++ks) {
                        union { int i[4]; bh8 v; } pu;
                        pu.i[0] = packhi(e[2 * ks][0],     e[2 * ks][1]);
                        pu.i[1] = packhi(e[2 * ks][2],     e[2 * ks][3]);
                        pu.i[2] = packhi(e[2 * ks + 1][0], e[2 * ks + 1][1]);
                        pu.i[3] = packhi(e[2 * ks + 1][2], e[2 * ks + 1][3]);
                        oacc[f] = __builtin_amdgcn_mfma_f32_16x16x32_bf16(vf[ks], pu.v, oacc[f], 0, 0, 0);
                    }
                }
                __builtin_amdgcn_s_setprio(0);
            }

            if (wave < 3)
                *(uint4*)&smem[(p ^ 1) * 1536 + wave * 512 + ksl * 8] = dA;
            else
                *(uint4*)&smem[3072 + (p ^ 1) * 1536 + vsl] = dA;
            if (wave == 0)
                *(uint4*)&smem[3072 + (p ^ 1) * 1536 + 512 + vsl] = dB;
            else if (wave == 1)
                *(uint4*)&smem[3072 + (p ^ 1) * 1536 + 1024 + vsl] = dB;
            p ^= 1;
            __syncthreads();
        }

        // partials: quad0 -> d0..3, quad1 -> d4..7, quad2/reg0 -> lsum
        const size_t prow = (size_t)(slice * 2 + half) * L_ATT;
#pragma unroll
        for (int f = 0; f < 2; ++f) {
            int qg = q0 + wave * 32 + f * 16 + col;
            if (quad < 2) {
                float4 o = { oacc[f][0], oacc[f][1], oacc[f][2], oacc[f][3] };
                *(float4*)(pnum + (prow + qg) * 8 + quad * 4) = o;
            } else if (quad == 2) {
                pls[prow + qg] = oacc[f][0];
            }
        }
        return;
    }

    // ---- posconv half ----
    const int gf = g - 1152;               // 576 = 144 * 4
    const int l0 = (gf % 144) * 16, n = gf / 144;
    const int t = wave;                    // oc-strip = wave id

    const int la = l0 + col;
    const int ya = la / 48, xa = la - ya * 48;

    f4 acc = (f4){0.f, 0.f, 0.f, 0.f};
    const short* vbase = vle + (size_t)n * L_ATT * 64;

#pragma unroll
    for (int q = 0; q < 9; ++q) {
        const int dy = q / 3 - 1, dx = q - (q / 3) * 3 - 1;
        const bool valid = ((unsigned)(ya + dy) < 48u) && ((unsigned)(xa + dx) < 48u);
        const short* ap = vbase + (size_t)(la + dy * 48 + dx) * 64 + quad * 8;
#pragma unroll
        for (int ks = 0; ks < 2; ++ks) {
            bh8 af = {0, 0, 0, 0, 0, 0, 0, 0};
            if (valid) af = *(const bh8*)(ap + ks * 32);
            bh8 bf = *(const bh8*)(wqp + ((size_t)q * 64 + t * 16 + col) * 64
                                   + ks * 32 + quad * 8);
            acc = __builtin_amdgcn_mfma_f32_16x16x32_bf16(af, bf, acc, 0, 0, 0);
        }
    }

    short* op = pcv + (size_t)n * L_ATT * 64;
    const int oc = t * 16 + col;
    const float bb = pbias[oc];
#pragma unroll
    for (int reg = 0; reg < 4; ++reg) {
        int l = l0 + quad * 4 + reg;
        op[(size_t)l * 64 + oc] = f2b(acc[reg] + bb);
    }
}

// ---------------------------------------------------------------------------
// comb: split-K combine + pcv add, packed bf16 ONCE per (n,l,ch) instead of
// once per oc-tile inside res (8x redundancy). battp[n][l][64] is bit-
// identical to the B-fragments res built in R4 (same packhi truncation).
// 576 blocks x 256: thread = (n, l, half-head); 16 lanes write 128B rows.
// ---------------------------------------------------------------------------
__global__ __launch_bounds__(256) void comb_kernel(
    const float* __restrict__ pnum, const float* __restrict__ pls,
    const short* __restrict__ pcv, short* __restrict__ battp)
{
    const int b = blockIdx.x;              // 576 = 4n * 144 lt
    const int n = b / 144, lt = b % 144;
    const int hh = threadIdx.x & 15;       // half-head: h = hh>>1, d-half = hh&1
    const int l  = lt * 16 + (threadIdx.x >> 4);
    const int h = hh >> 1, dh = hh & 1;

    const size_t p0 = (size_t)((n * 8 + h) * 2) * L_ATT;
    const size_t p1 = p0 + L_ATT;
    float4 a = *(const float4*)(pnum + (p0 + l) * 8 + dh * 4);
    float4 c = *(const float4*)(pnum + (p1 + l) * 8 + dh * 4);
    float inv = 1.0f / (pls[p0 + l] + pls[p1 + l]);
    short4 pv = *(const short4*)(pcv + ((size_t)n * L_ATT + l) * 64 + hh * 4);

    int2 o;
    o.x = packhi((a.x + c.x) * inv + b2f(pv.x), (a.y + c.y) * inv + b2f(pv.y));
    o.y = packhi((a.z + c.z) * inv + b2f(pv.z), (a.w + c.w) * inv + b2f(pv.w));
    *(int2*)(battp + ((size_t)n * L_ATT + l) * 64 + hh * 4) = o;
}

// ---------------------------------------------------------------------------
// res 1x1 conv, K=64: out = W.battp + res_b — pure GEMM, B-fragment is a
// single bh8 load (combine hoisted into comb_kernel). Flat grid 1152,
// XCD-swizzled; all 4 waves share the block's 8KB B panel via L1.
// ---------------------------------------------------------------------------
__global__ __launch_bounds__(256) void res_kernel(
    const short* __restrict__ battp, const short* __restrict__ reswb,
    const float* __restrict__ res_b, float* __restrict__ out)
{
    const int g = blockIdx.x;              // 1152 = 8 * 144
    const int xcd = g & 7, rr = g >> 3;    // rr < 144
    const int y = rr & 7, grp = rr >> 3;   // grp < 18
    const int code = grp * 8 + xcd;        // < 144
    const int l0 = (code % 36) * 64, oc0 = y * 64, n = code / 36;

    const int lane = threadIdx.x & 63, wave = threadIdx.x >> 6;
    const int col = lane & 15, quad = lane >> 4;
    const int ocb = oc0 + wave * 16;

    f4 acc[4];
#pragma unroll
    for (int nt = 0; nt < 4; ++nt) acc[nt] = (f4){0.f, 0.f, 0.f, 0.f};

#pragma unroll
    for (int ks = 0; ks < 2; ++ks) {
        bh8 af = *(const bh8*)(reswb + (size_t)(ocb + col) * 64 + ks * 32 + quad * 8);
        const int ch = ks * 32 + quad * 8;
#pragma unroll
        for (int nt = 0; nt < 4; ++nt) {
            const int l = l0 + nt * 16 + col;
            bh8 bf = *(const bh8*)(battp + ((size_t)n * L_ATT + l) * 64 + ch);
            acc[nt] = __builtin_amdgcn_mfma_f32_16x16x32_bf16(af, bf, acc[nt], 0, 0, 0);
        }
    }

#pragma unroll
    for (int nt = 0; nt < 4; ++nt) {
        int l = l0 + nt * 16 + col;
#pragma unroll
        for (int reg = 0; reg < 4; ++reg) {
            int oc = ocb + quad * 4 + reg;
            out[((size_t)n * 512 + oc) * L_ATT + l] = acc[nt][reg] + res_b[oc];
        }
    }
}

// ---------------------------------------------------------------------------
extern "C" void kernel_launch(void* const* d_in, const int* in_sizes, int n_in,
                              void* d_out, int out_size, void* d_ws, size_t ws_size,
                              hipStream_t stream)
{
    const float* x      = (const float*)d_in[0];
    const float* qkv_w  = (const float*)d_in[1];
    const float* qkv_b  = (const float*)d_in[2];
    const float* pos_w  = (const float*)d_in[3];
    const float* pos_b  = (const float*)d_in[4];
    const float* res_w  = (const float*)d_in[5];
    const float* res_b  = (const float*)d_in[6];
    float* out = (float*)d_out;

    char* ws = (char*)d_ws;
    float* pnum  = (float*)(ws);                    //  4,718,592 B: [64][2304][8]
    float* pls   = (float*)(ws + 4718592);          //    589,824 B: [64][2304]
    short* qt8   = (short*)(ws + 9437184);          //  1,179,648 B: [32][2304][8]
    short* kt8   = (short*)(ws + 10616832);         //  1,179,648 B: [32][2304][8]
    short* vt    = (short*)(ws + 11796480);         //  1,179,648 B: [32][8][2304]
    short* pcv   = (short*)(ws + 12976128);         //  1,179,648 B: [4][2304][64]
    short* wqb   = (short*)(ws + 14155776);         //    196,608 B: [192][512]
    short* reswb = (short*)(ws + 14352384);         //     65,536 B: [512][64]
    short* vle   = (short*)(ws + 14417920);         //  1,179,648 B: [4][2304][64]
    short* wqp   = (short*)(ws + 15597568);         //     73,728 B: [9][64][64]
    short* battp = (short*)(ws + 15671296);         //  1,179,648 B: [4][2304][64]

    prep_kernel<<<272, 256, 0, stream>>>(qkv_w, res_w, pos_w, wqb, reswb, wqp);
    qkv_kernel<<<864, 256, 0, stream>>>(x, wqb, qkv_b, qt8, kt8, vt, vle);
    attnpos_kernel<<<1728, 256, 0, stream>>>(qt8, kt8, vt, vle, wqp, pos_b, pnum, pls, pcv);
    comb_kernel<<<576, 256, 0, stream>>>(pnum, pls, pcv, battp);
    res_kernel<<<1152, 256, 0, stream>>>(battp, reswb, res_b, out);
}